// Round 3
// baseline (8742.822 us; speedup 1.0000x reference)
//
#include <hip/hip_runtime.h>

typedef unsigned short UST;
typedef unsigned int uint32;
typedef float f32x4 __attribute__((ext_vector_type(4)));
typedef short s16x8 __attribute__((ext_vector_type(8)));

// problem sizes: L=512 B=128 D=512 T=200 E=384 C=128 H=512 V=46

__device__ __forceinline__ float b2f(UST u) {
  uint32 x = ((uint32)u) << 16;
  union { uint32 u; float f; } v; v.u = x; return v.f;
}
__device__ __forceinline__ UST f2bf(float f) {
  union { float f; uint32 u; } v; v.f = f;
  uint32 r = (v.u + 0x7fffu + ((v.u >> 16) & 1u)) >> 16;
  return (UST)r;
}
__device__ __forceinline__ ushort4 f2bf4(float4 v) {
  ushort4 r; r.x = f2bf(v.x); r.y = f2bf(v.y); r.z = f2bf(v.z); r.w = f2bf(v.w); return r;
}
__device__ __forceinline__ float sigf(float x) { return 1.f / (1.f + __expf(-x)); }
__device__ __forceinline__ float tanhf_(float x) { return 2.f / (1.f + __expf(-2.f * x)) - 1.f; }

union U8 { unsigned long long u; ushort4 s; uint2 w; };

// coherent (IC-routed) accesses: relaxed agent atomics -> no cache inv/wb anywhere
__device__ __forceinline__ void st_flag(int* p, int v) {
  __hip_atomic_store(p, v, __ATOMIC_RELAXED, __HIP_MEMORY_SCOPE_AGENT);
}
__device__ __forceinline__ int ld_flag(const int* p) {
  return __hip_atomic_load(p, __ATOMIC_RELAXED, __HIP_MEMORY_SCOPE_AGENT);
}
__device__ __forceinline__ unsigned long long ld8(const void* p) {
  return __hip_atomic_load((const unsigned long long*)p, __ATOMIC_RELAXED, __HIP_MEMORY_SCOPE_AGENT);
}
__device__ __forceinline__ void st4(void* p, uint32 v) {
  __hip_atomic_store((uint32*)p, v, __ATOMIC_RELAXED, __HIP_MEMORY_SCOPE_AGENT);
}
__device__ __forceinline__ uint4 ld16c(const UST* p) {
  U8 a, b; a.u = ld8(p); b.u = ld8(p + 4);
  uint4 v; v.x = a.w.x; v.y = a.w.y; v.z = b.w.x; v.w = b.w.y; return v;
}

// drain own vmem (atomic stores acked at coherence point), then block-wide sync, then flag
__device__ __forceinline__ void signal_flag(int* fl, int idx, int val, int tid) {
  __atomic_signal_fence(__ATOMIC_SEQ_CST);
  __builtin_amdgcn_s_waitcnt(0);
  __atomic_signal_fence(__ATOMIC_SEQ_CST);
  __syncthreads();
  if (tid == 0) st_flag(&fl[idx * 16], val);
}
// all-to-all wait across 128 flags (init only). Deadline-bounded: past `dl`
// (s_memrealtime ticks) falls through so a protocol bug yields a fast wrong answer.
__device__ __forceinline__ void wait128f(int* fl, int val, int tid, unsigned long long dl) {
  if (tid < 128) {
    while (ld_flag(&fl[tid * 16]) < val) {
      if (__builtin_amdgcn_s_memrealtime() > dl) break;
      __builtin_amdgcn_s_sleep(1);
    }
  }
  __syncthreads();
}
// same-m-group wait: 64 flags. Steady-state syncs never cross the row-half boundary.
__device__ __forceinline__ void wait64f(int* fl, int val, int tid, unsigned long long dl) {
  if (tid < 64) {
    while (ld_flag(&fl[tid * 16]) < val) {
      if (__builtin_amdgcn_s_memrealtime() > dl) break;
      __builtin_amdgcn_s_sleep(1);
    }
  }
  __syncthreads();
}

struct Args {
  const float* lf; const int* ulen; const int* tr; const float* emb;
  const float* wih0; const float* whh0; const float* bih0; const float* bhh0;
  const float* wih1; const float* whh1; const float* bih1; const float* bhh1;
  const float* wih2; const float* whh2; const float* bih2; const float* bhh2;
  const float* phi_w; const float* phi_b; const float* key_w; const float* key_b;
  const float* val_w; const float* val_b; const float* out_w; const float* out_b;
  const float* ihx0; const float* icx0; const float* ihx1; const float* icx1;
  const float* ihx2; const float* icx2;
  int* bar; UST* wr; UST* xemb; UST* phi_bf; UST* keyfT; UST* valfT;
  UST* hx0; UST* hx1; UST* hx2; UST* ctx; UST* h2h; UST* cxh;
  float* out_logits; float* out_attn;
};

// ---------------- P1: zero flags, fragment-linear bf16 weights, xemb, phi_bf
// weight flat idx q: i=q&7 lane=(q>>3)&63 nt=(q>>9)&1 ks=(q>>10)&31 js=(q>>15)&63 cell=q>>21
// element = W[gr = js*32+nt*16+(lane&15)][k = ks*32+(lane>>4)*8+i], gate-row gr = j*4+g
// cell0 x layout: [emb 0..383 | h0 384..895 | ctx 896..1023]
__global__ void __launch_bounds__(256) kprep(Args A) {
  const long N0 = 8192;             // flag ints (32768 B)
  const long N1 = 3L * 2048 * 1024; // weights
  const long N2 = 200L * 128 * 384; // xemb
  const long N3 = 128L * 512;       // phi
  long total = N0 + N1 + N2 + N3;
  long stride = (long)gridDim.x * blockDim.x;
  for (long ii = (long)blockIdx.x * 256 + threadIdx.x; ii < total; ii += stride) {
    long j = ii;
    if (j < N0) { A.bar[j] = 0; continue; }
    j -= N0;
    if (j < N1) {
      int q = (int)j;
      int i = q & 7, lane = (q >> 3) & 63, nt = (q >> 9) & 1, ks = (q >> 10) & 31;
      int js = (q >> 15) & 63, cell = q >> 21;
      int gr = js * 32 + nt * 16 + (lane & 15);
      int jc = gr >> 2, g = gr & 3, k = ks * 32 + (lane >> 4) * 8 + i;
      const float* wi = cell == 0 ? A.wih0 : cell == 1 ? A.wih1 : A.wih2;
      const float* wh = cell == 0 ? A.whh0 : cell == 1 ? A.whh1 : A.whh2;
      float v;
      if (cell == 0)
        v = (k < 384) ? wi[(g * 512 + jc) * 512 + k]
          : (k < 896) ? wh[(g * 512 + jc) * 512 + k - 384]
                      : wi[(g * 512 + jc) * 512 + k - 512];
      else
        v = (k < 512) ? wi[(g * 512 + jc) * 512 + k] : wh[(g * 512 + jc) * 512 + k - 512];
      A.wr[j] = f2bf(v);
      continue;
    }
    j -= N1;
    if (j < N2) {
      int t = (int)(j / 49152); int r = (int)(j % 49152); int bb = r / 384; int e = r - bb * 384;
      int ch = (t == 0) ? 0 : A.tr[(t - 1) * 128 + bb];
      A.xemb[j] = f2bf(A.emb[ch * 384 + e]);
      continue;
    }
    j -= N2;
    A.phi_bf[j] = f2bf(A.phi_w[j]);
  }
}

// ---------------- P2: keyfT/valfT = (lf . W^T + b), stored [B][C][L] bf16
__global__ void __launch_bounds__(256) kkv(Args A) {
  __shared__ __attribute__((aligned(16))) char sm[17408 + 34816];
  UST (*A_lds)[136] = (UST(*)[136])sm;
  UST (*W_lds)[136] = (UST(*)[136])(sm + 17408);
  float* sbuf = (float*)(sm + 17408);
  int tid = threadIdx.x, lane = tid & 63, wv = tid >> 6, ln = lane & 15, qd = lane >> 4;
  int blk = blockIdx.x;
  int b = blk >> 4, lt = (blk >> 1) & 7, kv = blk & 1;
  int l0 = lt * 64;
  const float* W = kv ? A.val_w : A.key_w;
  const float* bs = kv ? A.val_b : A.key_b;
  UST* outp = kv ? A.valfT : A.keyfT;
  f32x4 acc[8];
#pragma unroll
  for (int nt = 0; nt < 8; ++nt) {
    float x = bs[nt * 16 + ln];
    f32x4 t; t[0] = x; t[1] = x; t[2] = x; t[3] = x; acc[nt] = t;
  }
  for (int cc = 0; cc < 4; ++cc) {
    int d0 = cc * 128;
#pragma unroll
    for (int it = 0; it < 8; ++it) {
      int idx = it * 256 + tid, row = idx >> 5, seg = idx & 31;
      float4 v = *(const float4*)(A.lf + ((size_t)(l0 + row) * 128 + b) * 512 + d0 + seg * 4);
      *(ushort4*)&A_lds[row][seg * 4] = f2bf4(v);
    }
#pragma unroll
    for (int it = 0; it < 16; ++it) {
      int idx = it * 256 + tid, row = idx >> 5, seg = idx & 31;
      float4 v = *(const float4*)(W + (size_t)row * 512 + d0 + seg * 4);
      *(ushort4*)&W_lds[row][seg * 4] = f2bf4(v);
    }
    __syncthreads();
#pragma unroll
    for (int ks = 0; ks < 4; ++ks) {
      s16x8 av = *(const s16x8*)&A_lds[wv * 16 + ln][ks * 32 + qd * 8];
#pragma unroll
      for (int nt = 0; nt < 8; ++nt) {
        s16x8 bv = *(const s16x8*)&W_lds[nt * 16 + ln][ks * 32 + qd * 8];
        acc[nt] = __builtin_amdgcn_mfma_f32_16x16x32_bf16(av, bv, acc[nt], 0, 0, 0);
      }
    }
    __syncthreads();
  }
#pragma unroll
  for (int nt = 0; nt < 8; ++nt)
#pragma unroll
    for (int r = 0; r < 4; ++r)
      sbuf[(wv * 16 + qd * 4 + r) * 128 + nt * 16 + ln] = acc[nt][r];
  __syncthreads();
  int c2 = tid >> 1, lh = tid & 1;
  for (int g8 = 0; g8 < 4; ++g8) {
    UST tmp[8];
#pragma unroll
    for (int i = 0; i < 8; ++i) tmp[i] = f2bf(sbuf[(lh * 32 + g8 * 8 + i) * 128 + c2]);
    *(uint4*)(outp + ((size_t)b * 128 + c2) * 512 + l0 + lh * 32 + g8 * 8) = *(uint4*)tmp;
  }
}

// ---------------- cell staging: X is 64 rows x 512 k-cols, 16B chunks XOR-swizzled.
// per-thread geometry: cS = tid&63 (fixed chunk column), rB = tid>>6; row r = it*4+rB.
__device__ __forceinline__ void stage_plain(int cS, int rB, const UST* src, UST (*X)[512]) {
  uint4 rg[16];
#pragma unroll
  for (int it = 0; it < 16; ++it)
    rg[it] = ld16c(src + (it * 4 + rB) * 512 + cS * 8);
  __syncthreads();  // prior readers of X are done
#pragma unroll
  for (int it = 0; it < 16; ++it) {
    int r = it * 4 + rB;
    *(uint4*)&X[r][(cS ^ (r & 7)) * 8] = rg[it];
  }
  __syncthreads();
}
// emb staging: chunks 0..47 only (plain loads; xemb written by kprep). Leading barrier
// is supplied by the preceding signal/wait.
__device__ __forceinline__ void stage_emb(int cS, int rB, const UST* xe, UST (*X)[512]) {
  if (cS < 48) {
    uint4 rg[16];
#pragma unroll
    for (int it = 0; it < 16; ++it)
      rg[it] = *(const uint4*)(xe + (it * 4 + rB) * 384 + cS * 8);
#pragma unroll
    for (int it = 0; it < 16; ++it) {
      int r = it * 4 + rB;
      *(uint4*)&X[r][(cS ^ (r & 7)) * 8] = rg[it];
    }
  }
  __syncthreads();
}
// ctx staging: chunks 48..63 only (coherent loads). Leading barrier from preceding wait.
__device__ __forceinline__ void stage_ctx(int cS, int rB, const UST* cxr, UST (*X)[512]) {
  if (cS >= 48) {
    uint4 rg[16];
#pragma unroll
    for (int it = 0; it < 16; ++it)
      rg[it] = ld16c(cxr + (it * 4 + rB) * 128 + (cS - 48) * 8);
#pragma unroll
    for (int it = 0; it < 16; ++it) {
      int r = it * 4 + rB;
      *(uint4*)&X[r][(cS ^ (r & 7)) * 8] = rg[it];
    }
  }
  __syncthreads();
}
// generic K-split compute: waves split SPW*4 local slices; local slice ls = w*SPW+j,
// weight k-slice ksg = ksgBase+ls, X chunk col = chunkBase + ls*4 + qd.
template <int SPW>
__device__ __forceinline__ void compute_r(int w, int ln, int qd, int lane,
    const UST* wb, int ksgBase, int chunkBase, UST (*X)[512], f32x4 acc[4][2]) {
#pragma unroll
  for (int j = 0; j < SPW; ++j) {
    int ls = w * SPW + j;
    int ksg = ksgBase + ls;
    s16x8 b0 = *(const s16x8*)(wb + ((size_t)(ksg * 2 + 0) * 64 + lane) * 8);
    s16x8 b1 = *(const s16x8*)(wb + ((size_t)(ksg * 2 + 1) * 64 + lane) * 8);
#pragma unroll
    for (int rt = 0; rt < 4; ++rt) {
      int r = rt * 16 + ln, c = chunkBase + ls * 4 + qd;
      s16x8 av = *(const s16x8*)&X[r][(c ^ (r & 7)) * 8];
      acc[rt][0] = __builtin_amdgcn_mfma_f32_16x16x32_bf16(av, b0, acc[rt][0], 0, 0, 0);
      acc[rt][1] = __builtin_amdgcn_mfma_f32_16x16x32_bf16(av, b1, acc[rt][1], 0, 0, 0);
    }
  }
}
__device__ __forceinline__ void zacc(f32x4 acc[4][2]) {
#pragma unroll
  for (int rt = 0; rt < 4; ++rt)
#pragma unroll
    for (int nt = 0; nt < 2; ++nt) {
      acc[rt][nt][0] = 0.f; acc[rt][nt][1] = 0.f; acc[rt][nt][2] = 0.f; acc[rt][nt][3] = 0.f;
    }
}
__device__ __forceinline__ void cacc(f32x4 dst[4][2], const f32x4 src[4][2]) {
#pragma unroll
  for (int rt = 0; rt < 4; ++rt)
#pragma unroll
    for (int nt = 0; nt < 2; ++nt) dst[rt][nt] = src[rt][nt];
}
// cross-wave K-reduce in LDS + gate nonlinearity + coherent h store
__device__ __forceinline__ void cell_epilogue(const Args& A, int cell, int t, int m, int j0,
    int tid, int w, int ln, int qd, f32x4 acc[4][2], float* FB,
    const float* bias8, float* cr, UST* hdst) {
  __syncthreads();
#pragma unroll
  for (int rt = 0; rt < 4; ++rt)
#pragma unroll
    for (int nt = 0; nt < 2; ++nt)
#pragma unroll
      for (int reg = 0; reg < 4; ++reg)
        FB[w * 2112 + (rt * 16 + qd * 4 + reg) * 33 + nt * 16 + ln] = acc[rt][nt][reg];
  __syncthreads();
  int row = tid >> 2, q4 = tid & 3, grow = m * 64 + row;
  uint32 upack = 0;
#pragma unroll
  for (int jj = 0; jj < 2; ++jj) {
    int gc = (q4 * 2 + jj) * 4;
    int o = row * 33 + gc;
    float g0 = FB[o] + FB[2112 + o] + FB[4224 + o] + FB[6336 + o] + bias8[jj * 4 + 0];
    float g1 = FB[o + 1] + FB[2112 + o + 1] + FB[4224 + o + 1] + FB[6336 + o + 1] + bias8[jj * 4 + 1];
    float g2 = FB[o + 2] + FB[2112 + o + 2] + FB[4224 + o + 2] + FB[6336 + o + 2] + bias8[jj * 4 + 2];
    float g3 = FB[o + 3] + FB[2112 + o + 3] + FB[4224 + o + 3] + FB[6336 + o + 3] + bias8[jj * 4 + 3];
    float cn = sigf(g1) * cr[jj] + sigf(g0) * tanhf_(g2);
    float hv = sigf(g3) * tanhf_(cn);
    cr[jj] = cn;
    upack |= ((uint32)f2bf(hv)) << (16 * jj);
  }
  st4(hdst + grow * 512 + j0 + q4 * 2, upack);
  if (cell == 2) *(uint32*)(A.h2h + ((size_t)t * 128 + grow) * 512 + j0 + q4 * 2) = upack;
}

// ---------------- attention (blocks 128..255, one batch row each)
// K and V live in per-thread REGISTERS (preloaded once): per-step memory = phi stream only.
__device__ __forceinline__ void attend_f(const Args& A, int t, int p, int b, int tid,
    int lane, int wv, char* smraw, const uint4 (&rgK)[32], const uint4 (&rgV)[32]) {
  float* att_h = (float*)smraw;                       // 512
  float* att_q = att_h + 512;                         // 256
  float* att_c = att_q + 256;                         // 128
  float* att_red = att_c + 128;                       // 16
  float (*e_part)[512] = (float(*)[512])(att_red + 16);
  const UST* hx2p = A.hx2 + p * 65536;
  if (tid < 128) {
    U8 v; v.u = ld8(hx2p + b * 512 + tid * 4);
    att_h[tid * 4 + 0] = b2f(v.s.x); att_h[tid * 4 + 1] = b2f(v.s.y);
    att_h[tid * 4 + 2] = b2f(v.s.z); att_h[tid * 4 + 3] = b2f(v.s.w);
  }
  __syncthreads();
  int c = tid & 127, half = tid >> 7;
  { // q = phi_b + phi . hx2 (phi streamed from L2; shared across 16 blocks/XCD)
    float acc = half ? 0.f : A.phi_b[c];
    const UST* pr = A.phi_bf + c * 512 + half * 256;
    const float* hh = att_h + half * 256;
#pragma unroll 4
    for (int k = 0; k < 256; k += 8) {
      uint4 v = *(const uint4*)(pr + k);
      const UST* us = (const UST*)&v;
#pragma unroll
      for (int i = 0; i < 8; ++i) acc += b2f(us[i]) * hh[k + i];
    }
    att_q[tid] = acc;
  }
  __syncthreads();
  if (tid < 128) att_q[tid] += att_q[tid + 128];
  __syncthreads();
  { // energies from K registers: thread (cg,lg) covers c in [cg*32,cg*32+32), l = lg*8+i
    int cg = tid >> 6, lg = tid & 63;
    float ep[8] = {0, 0, 0, 0, 0, 0, 0, 0};
#pragma unroll
    for (int i = 0; i < 32; ++i) {
      float qv = att_q[cg * 32 + i];
      const UST* us = (const UST*)&rgK[i];
#pragma unroll
      for (int j = 0; j < 8; ++j) ep[j] += qv * b2f(us[j]);
    }
#pragma unroll
    for (int i = 0; i < 8; ++i) e_part[cg][lg * 8 + i] = ep[i];
  }
  __syncthreads();
  float e0 = e_part[0][2 * tid] + e_part[1][2 * tid] + e_part[2][2 * tid] + e_part[3][2 * tid];
  float e1 = e_part[0][2 * tid + 1] + e_part[1][2 * tid + 1] + e_part[2][2 * tid + 1] + e_part[3][2 * tid + 1];
  float mx = fmaxf(e0, e1);
#pragma unroll
  for (int off = 32; off; off >>= 1) mx = fmaxf(mx, __shfl_xor(mx, off));
  if (lane == 0) att_red[wv] = mx;
  __syncthreads();
  mx = fmaxf(fmaxf(att_red[0], att_red[1]), fmaxf(att_red[2], att_red[3]));
  int len = A.ulen[b];
  float x0 = (2 * tid < len) ? __expf(e0 - mx) : 0.f;
  float x1 = (2 * tid + 1 < len) ? __expf(e1 - mx) : 0.f;
  float s = x0 + x1;
#pragma unroll
  for (int off = 32; off; off >>= 1) s += __shfl_xor(s, off);
  if (lane == 0) att_red[8 + wv] = s;
  __syncthreads();
  s = att_red[8] + att_red[9] + att_red[10] + att_red[11];
  float inv = 1.f / fmaxf(s, 1e-12f);
  float a0 = x0 * inv, a1 = x1 * inv;
  float* esm = &e_part[0][0];
  esm[2 * tid] = a0; esm[2 * tid + 1] = a1;
  if (t >= 0) {
    float2 st; st.x = a0; st.y = a1;
    *(float2*)(A.out_attn + ((size_t)t * 128 + b) * 512 + 2 * tid) = st;
  }
  __syncthreads();
  { // ctx[c] = sum_l a_l * V[c][l] from V registers; thread (c,half) covers l half*256..+256
    float acc = 0.f;
    const float* aa = esm + half * 256;
#pragma unroll
    for (int i = 0; i < 32; ++i) {
      const UST* us = (const UST*)&rgV[i];
#pragma unroll
      for (int j = 0; j < 8; ++j) acc += aa[i * 8 + j] * b2f(us[j]);
    }
    att_q[tid] = acc;
  }
  __syncthreads();
  if (tid < 128) att_c[tid] = att_q[tid] + att_q[tid + 128];
  __syncthreads();
  if (tid < 64) {
    float cv0 = att_c[2 * tid], cv1 = att_c[2 * tid + 1];
    uint32 u = (uint32)f2bf(cv0) | ((uint32)f2bf(cv1) << 16);
    st4(A.ctx + p * 16384 + b * 128 + 2 * tid, u);
    if (t >= 0) *(uint32*)(A.cxh + ((size_t)t * 128 + b) * 128 + 2 * tid) = u;
  }
}

// ---------------- main persistent kernel. PLAIN launch (not cooperative): sync is
// hand-rolled flags; co-residency by capacity arithmetic (LDS 64KB, grid 256 <= 256 CUs,
// 1 block/CU at 4 waves = 1 wave/SIMD; __launch_bounds__(256,1) allows up to 512 VGPR
// so neither branch spills). Flags indexed sid = m*64+js; steady-state waits are 64-wide
// within one m-half. All waits deadline-bounded (~1 s).
// Per-step schedule (cell blocks) — every flag hop is hidden under independent work:
//   seg0: [mc2 t+1] stage h2(t-1), cell2 K16..31            (overlaps attend)
//   seg1: [mat t+1] stage ctx, cell0 sl28..31, epi0, sig c0
//   seg2: stage emb(t+1), cell0' sl0..11                    (hides c0 hop)
//   seg3: [mc0 t+2] stage h0(t) ONCE -> cell1 K0..15 AND cell0' sl12..27, epi1, sig c1
//   seg4: [mc1 t+2] stage h1(t) ONCE -> cell2 K0..15 AND cell1' K16..31, epi2, sig c2
// (cell0' / cell1' = next step's accumulators, rotated at loop end.)
__global__ void __launch_bounds__(256, 1) kmain(Args A) {
  __shared__ __attribute__((aligned(16))) char smraw[65536];
  unsigned long long dl = __builtin_amdgcn_s_memrealtime() + 100000000ull;
  int blk = blockIdx.x, tid = threadIdx.x;
  int lane = tid & 63, w = tid >> 6, ln = lane & 15, qd = lane >> 4;
  int* c0f = A.bar;
  int* c1f = A.bar + 2048;
  int* c2f = A.bar + 4096;
  int* attf = A.bar + 6144;
  if (blk < 128) {
    UST (*X)[512] = (UST(*)[512])smraw;   // 64 KB staging
    float* FB = (float*)smraw;            // 33,792 B epilogue reduce (aliased)
    // same-XCD weight-slab pairing: blk and blk^8 share js and land on one XCD
    int js = ((blk >> 4) << 3) | (blk & 7);
    int m = (blk >> 3) & 1;
    int j0 = js * 8;
    int sid = m * 64 + js;
    int* mc0 = c0f + m * 1024;   // this half's 64 flags
    int* mc1 = c1f + m * 1024;
    int* mc2 = c2f + m * 1024;
    int* mat = attf + m * 1024;
    int cS = tid & 63, rB = tid >> 6;
    float bias[3][8]; float cr[3][2];
    {
      const float* bihA[3] = {A.bih0, A.bih1, A.bih2};
      const float* bhhA[3] = {A.bhh0, A.bhh1, A.bhh2};
      const float* icxA[3] = {A.icx0, A.icx1, A.icx2};
      const float* ihxA[3] = {A.ihx0, A.ihx1, A.ihx2};
      UST* hxA[3] = {A.hx0, A.hx1, A.hx2};
      int q4 = tid & 3;
#pragma unroll
      for (int cI = 0; cI < 3; ++cI) {
#pragma unroll
        for (int jj = 0; jj < 2; ++jj) {
          int col = j0 + q4 * 2 + jj;
          for (int g = 0; g < 4; ++g)
            bias[cI][jj * 4 + g] = bihA[cI][g * 512 + col] + bhhA[cI][g * 512 + col];
          cr[cI][jj] = icxA[cI][col];
        }
        int row = tid >> 2, grow = m * 64 + row, col0 = j0 + q4 * 2;
        uint32 u = (uint32)f2bf(ihxA[cI][col0]) | ((uint32)f2bf(ihxA[cI][col0 + 1]) << 16);
        st4(hxA[cI] + 65536 + grow * 512 + col0, u);  // init into slot 1
      }
    }
    signal_flag(c2f, sid, 1, tid);
    wait128f(c2f, 1, tid, dl);
    const UST* wrj0 = A.wr + (size_t)js * 32768;
    const UST* wrj1 = wrj0 + 2097152;
    const UST* wrj2 = wrj0 + 4194304;
    f32x4 acc0[4][2], acc1[4][2], acc2[4][2], acc0n[4][2], acc1n[4][2];
    zacc(acc0); zacc(acc1); zacc(acc2); zacc(acc0n); zacc(acc1n);
    // prologue for t=0 (all init state, slot 1):
    {
      const UST* xe0 = A.xemb + m * 64 * 384;
      const UST* h0i = A.hx0 + 65536 + m * 64 * 512;
      const UST* h1i = A.hx1 + 65536 + m * 64 * 512;
      stage_emb(cS, rB, xe0, X);
      compute_r<3>(w, ln, qd, lane, wrj0, 0, 0, X, acc0);   // emb(0) -> sl0..11
      stage_plain(cS, rB, h0i, X);
      compute_r<4>(w, ln, qd, lane, wrj0, 12, 0, X, acc0);  // h0(init) -> sl12..27
      stage_plain(cS, rB, h1i, X);
      compute_r<4>(w, ln, qd, lane, wrj1, 16, 0, X, acc1);  // h1(init) -> cell1 K16..31
    }
    for (int t = 0; t < 200; ++t) {
      int p = t & 1, po = p ^ 1;
      const UST* h2r = A.hx2 + po * 65536 + m * 64 * 512;
      const UST* cxr = A.ctx + po * 16384 + m * 64 * 128;
      // seg0: cell2 recurrent half (h2(t-1)); overlaps attend(t-1) on other CUs
      wait64f(mc2, t + 1, tid, dl);
      stage_plain(cS, rB, h2r, X);
      compute_r<4>(w, ln, qd, lane, wrj2, 16, 0, X, acc2);
      // seg1: ctx(t-1) slices + epilogue0
      wait64f(mat, t + 1, tid, dl);
      stage_ctx(cS, rB, cxr, X);
      compute_r<1>(w, ln, qd, lane, wrj0, 28, 48, X, acc0);
      cell_epilogue(A, 0, t, m, j0, tid, w, ln, qd, acc0, FB, bias[0], cr[0], A.hx0 + p * 65536);
      signal_flag(c0f, sid, t + 2, tid);
      // seg2: emb(t+1) -> next cell0 sl0..11 (wait-free; hides the c0 hop)
      if (t < 199) {
        const UST* xe1 = A.xemb + (size_t)(t + 1) * 49152 + m * 64 * 384;
        stage_emb(cS, rB, xe1, X);
        compute_r<3>(w, ln, qd, lane, wrj0, 0, 0, X, acc0n);
      }
      // seg3: h0(t) staged once -> cell1 K0..15 + next cell0 sl12..27
      const UST* h0n = A.hx0 + p * 65536 + m * 64 * 512;
      wait64f(mc0, t + 2, tid, dl);
      stage_plain(cS, rB, h0n, X);
      compute_r<4>(w, ln, qd, lane, wrj1, 0, 0, X, acc1);
      compute_r<4>(w, ln, qd, lane, wrj0, 12, 0, X, acc0n);
      cell_epilogue(A, 1, t, m, j0, tid, w, ln, qd, acc1, FB, bias[1], cr[1], A.hx1 + p * 65536);
      signal_flag(c1f, sid, t + 2, tid);
      // seg4: h1(t) staged once -> cell2 K0..15 + next cell1 K16..31
      const UST* h1n = A.hx1 + p * 65536 + m * 64 * 512;
      wait64f(mc1, t + 2, tid, dl);
      stage_plain(cS, rB, h1n, X);
      compute_r<4>(w, ln, qd, lane, wrj2, 0, 0, X, acc2);
      compute_r<4>(w, ln, qd, lane, wrj1, 16, 0, X, acc1n);
      cell_epilogue(A, 2, t, m, j0, tid, w, ln, qd, acc2, FB, bias[2], cr[2], A.hx2 + p * 65536);
      signal_flag(c2f, sid, t + 2, tid);
      // rotate carried accumulators
      cacc(acc0, acc0n); cacc(acc1, acc1n);
      zacc(acc0n); zacc(acc1n); zacc(acc2);
    }
  } else {
    int b = blk - 128;
    int* mc2a = c2f + (b >> 6) * 1024;  // this row's m-half c2 flags
    // preload K,V into registers (written by kkv, which completed before kmain)
    uint4 rgK[32], rgV[32];
    {
      int cg = tid >> 6, lg = tid & 63;
      const UST* kb = A.keyfT + (size_t)b * 65536 + lg * 8;
#pragma unroll
      for (int i = 0; i < 32; ++i)
        rgK[i] = *(const uint4*)(kb + (size_t)(cg * 32 + i) * 512);
      int c = tid & 127, half = tid >> 7;
      const UST* vb = A.valfT + (size_t)b * 65536 + (size_t)c * 512 + half * 256;
#pragma unroll
      for (int i = 0; i < 32; ++i)
        rgV[i] = *(const uint4*)(vb + i * 8);
    }
    wait128f(c2f, 1, tid, dl);
    attend_f(A, -1, 1, b, tid, lane, w, smraw, rgK, rgV);
    signal_flag(attf, b, 1, tid);
    for (int t = 0; t < 200; ++t) {
      wait64f(mc2a, t + 2, tid, dl);
      attend_f(A, t, t & 1, b, tid, lane, w, smraw, rgK, rgV);
      signal_flag(attf, b, t + 2, tid);
    }
  }
}

// ---------------- epilogue: logits[t,b,v] = [hx2,ctx] . out_w^T + out_b
__global__ void __launch_bounds__(256) kepi(Args A) {
  __shared__ UST ow[46 * 648];
  __shared__ float ob[46];
  int t = blockIdx.x, tid = threadIdx.x;
  for (int i = tid; i < 46 * 640; i += 256) {
    int v = i / 640, k = i - v * 640; ow[v * 648 + k] = f2bf(A.out_w[i]);
  }
  if (tid < 46) ob[tid] = A.out_b[tid];
  __syncthreads();
  for (int oi = tid; oi < 128 * 46; oi += 256) {
    int bb = oi / 46, v = oi - bb * 46;
    const UST* xh = A.h2h + ((size_t)t * 128 + bb) * 512;
    const UST* xc = A.cxh + ((size_t)t * 128 + bb) * 128;
    const UST* wrow = &ow[v * 648];
    float acc = ob[v];
    for (int k = 0; k < 512; k += 8) {
      uint4 xv = *(const uint4*)(xh + k);
      uint4 wv4 = *(const uint4*)(wrow + k);
      const UST* xs = (const UST*)&xv; const UST* wl = (const UST*)&wv4;
#pragma unroll
      for (int i = 0; i < 8; ++i) acc += b2f(xs[i]) * b2f(wl[i]);
    }
    for (int k = 0; k < 128; k += 8) {
      uint4 xv = *(const uint4*)(xc + k);
      uint4 wv4 = *(const uint4*)(wrow + 512 + k);
      const UST* xs = (const UST*)&xv; const UST* wl = (const UST*)&wv4;
#pragma unroll
      for (int i = 0; i < 8; ++i) acc += b2f(xs[i]) * b2f(wl[i]);
    }
    A.out_logits[((size_t)t * 128 + bb) * 46 + v] = acc;
  }
}

extern "C" void kernel_launch(void* const* d_in, const int* in_sizes, int n_in,
                              void* d_out, int out_size, void* d_ws, size_t ws_size,
                              hipStream_t stream) {
  (void)in_sizes; (void)n_in; (void)out_size; (void)ws_size;
  Args a;
  a.lf = (const float*)d_in[0]; a.ulen = (const int*)d_in[1]; a.tr = (const int*)d_in[2];
  a.emb = (const float*)d_in[3];
  a.wih0 = (const float*)d_in[4]; a.whh0 = (const float*)d_in[5]; a.bih0 = (const float*)d_in[6]; a.bhh0 = (const float*)d_in[7];
  a.wih1 = (const float*)d_in[8]; a.whh1 = (const float*)d_in[9]; a.bih1 = (const float*)d_in[10]; a.bhh1 = (const float*)d_in[11];
  a.wih2 = (const float*)d_in[12]; a.whh2 = (const float*)d_in[13]; a.bih2 = (const float*)d_in[14]; a.bhh2 = (const float*)d_in[15];
  a.phi_w = (const float*)d_in[16]; a.phi_b = (const float*)d_in[17];
  a.key_w = (const float*)d_in[18]; a.key_b = (const float*)d_in[19];
  a.val_w = (const float*)d_in[20]; a.val_b = (const float*)d_in[21];
  a.out_w = (const float*)d_in[22]; a.out_b = (const float*)d_in[23];
  a.ihx0 = (const float*)d_in[24]; a.icx0 = (const float*)d_in[25];
  a.ihx1 = (const float*)d_in[26]; a.icx1 = (const float*)d_in[27];
  a.ihx2 = (const float*)d_in[28]; a.icx2 = (const float*)d_in[29];
  char* ws = (char*)d_ws;
  a.bar    = (int*)ws;                   // 32,768 B (4 flag arrays x 128 x 16 ints)
  a.wr     = (UST*)(ws + 32768);         // 12,582,912 B
  a.xemb   = (UST*)(ws + 12615680);      // 19,660,800 B
  a.phi_bf = (UST*)(ws + 32276480);      // 131,072 B
  a.keyfT  = (UST*)(ws + 32407552);      // 16,777,216 B
  a.valfT  = (UST*)(ws + 49184768);      // 16,777,216 B
  a.hx0    = (UST*)(ws + 65961984);      // 262,144 B (2 slots)
  a.hx1    = (UST*)(ws + 66224128);      // 262,144 B
  a.hx2    = (UST*)(ws + 66486272);      // 262,144 B
  a.ctx    = (UST*)(ws + 66748416);      // 65,536 B (2 slots)
  a.h2h    = (UST*)(ws + 66813952);      // 26,214,400 B
  a.cxh    = (UST*)(ws + 93028352);      // 6,553,600 B -> total 99,581,952 B
  a.out_logits = (float*)d_out;
  a.out_attn   = (float*)d_out + 1177600;
  kprep<<<4096, 256, 0, stream>>>(a);
  kkv<<<2048, 256, 0, stream>>>(a);
  kmain<<<256, 256, 0, stream>>>(a);
  kepi<<<200, 256, 0, stream>>>(a);
}

// Round 4
// 6709.364 us; speedup vs baseline: 1.3031x; 1.3031x over previous
//
#include <hip/hip_runtime.h>

typedef unsigned short UST;
typedef unsigned int uint32;
typedef float f32x4 __attribute__((ext_vector_type(4)));
typedef short s16x8 __attribute__((ext_vector_type(8)));

// problem sizes: L=512 B=128 D=512 T=200 E=384 C=128 H=512 V=46

__device__ __forceinline__ float b2f(UST u) {
  uint32 x = ((uint32)u) << 16;
  union { uint32 u; float f; } v; v.u = x; return v.f;
}
__device__ __forceinline__ UST f2bf(float f) {
  union { float f; uint32 u; } v; v.f = f;
  uint32 r = (v.u + 0x7fffu + ((v.u >> 16) & 1u)) >> 16;
  return (UST)r;
}
__device__ __forceinline__ ushort4 f2bf4(float4 v) {
  ushort4 r; r.x = f2bf(v.x); r.y = f2bf(v.y); r.z = f2bf(v.z); r.w = f2bf(v.w); return r;
}
__device__ __forceinline__ float sigf(float x) { return 1.f / (1.f + __expf(-x)); }
__device__ __forceinline__ float tanhf_(float x) { return 2.f / (1.f + __expf(-2.f * x)) - 1.f; }

union U8 { unsigned long long u; ushort4 s; uint2 w; };

// coherent (IC-routed) accesses: relaxed agent atomics -> no cache inv/wb anywhere
__device__ __forceinline__ void st_flag(int* p, int v) {
  __hip_atomic_store(p, v, __ATOMIC_RELAXED, __HIP_MEMORY_SCOPE_AGENT);
}
__device__ __forceinline__ int ld_flag(const int* p) {
  return __hip_atomic_load(p, __ATOMIC_RELAXED, __HIP_MEMORY_SCOPE_AGENT);
}
__device__ __forceinline__ unsigned long long ld8(const void* p) {
  return __hip_atomic_load((const unsigned long long*)p, __ATOMIC_RELAXED, __HIP_MEMORY_SCOPE_AGENT);
}
__device__ __forceinline__ void st4(void* p, uint32 v) {
  __hip_atomic_store((uint32*)p, v, __ATOMIC_RELAXED, __HIP_MEMORY_SCOPE_AGENT);
}
__device__ __forceinline__ uint4 ld16c(const UST* p) {
  U8 a, b; a.u = ld8(p); b.u = ld8(p + 4);
  uint4 v; v.x = a.w.x; v.y = a.w.y; v.z = b.w.x; v.w = b.w.y; return v;
}

// drain own vmem (atomic stores acked at coherence point), then block-wide sync, then flag
__device__ __forceinline__ void signal_flag(int* fl, int idx, int val, int tid) {
  __atomic_signal_fence(__ATOMIC_SEQ_CST);
  __builtin_amdgcn_s_waitcnt(0);
  __atomic_signal_fence(__ATOMIC_SEQ_CST);
  __syncthreads();
  if (tid == 0) st_flag(&fl[idx * 16], val);
}
// all-to-all wait across 128 flags (init only). Deadline-bounded: past `dl`
// (s_memrealtime ticks) falls through so a protocol bug yields a fast wrong answer.
__device__ __forceinline__ void wait128f(int* fl, int val, int tid, unsigned long long dl) {
  if (tid < 128) {
    while (ld_flag(&fl[tid * 16]) < val) {
      if (__builtin_amdgcn_s_memrealtime() > dl) break;
      __builtin_amdgcn_s_sleep(1);
    }
  }
  __syncthreads();
}

struct Args {
  const float* lf; const int* ulen; const int* tr; const float* emb;
  const float* wih0; const float* whh0; const float* bih0; const float* bhh0;
  const float* wih1; const float* whh1; const float* bih1; const float* bhh1;
  const float* wih2; const float* whh2; const float* bih2; const float* bhh2;
  const float* phi_w; const float* phi_b; const float* key_w; const float* key_b;
  const float* val_w; const float* val_b; const float* out_w; const float* out_b;
  const float* ihx0; const float* icx0; const float* ihx1; const float* icx1;
  const float* ihx2; const float* icx2;
  int* bar; UST* wr; UST* xemb; UST* phi_bf; UST* keyfT; UST* valfT;
  UST* hx0; UST* hx1; UST* hx2; UST* ctx; UST* h2h; UST* cxh;
  float* out_logits; float* out_attn;
};

// ---------------- P1: zero flags, fragment-linear bf16 weights, xemb, phi_bf
// weight flat idx q: i=q&7 lane=(q>>3)&63 nt=(q>>9)&1 ks=(q>>10)&31 js=(q>>15)&63 cell=q>>21
// element = W[gr = js*32+nt*16+(lane&15)][k = ks*32+(lane>>4)*8+i], gate-row gr = j*4+g
// cell0 x layout: [emb 0..383 | h0 384..895 | ctx 896..1023]
__global__ void __launch_bounds__(256) kprep(Args A) {
  const long N0 = 8192;             // flag ints (32768 B)
  const long N1 = 3L * 2048 * 1024; // weights
  const long N2 = 200L * 128 * 384; // xemb
  const long N3 = 128L * 512;       // phi
  long total = N0 + N1 + N2 + N3;
  long stride = (long)gridDim.x * blockDim.x;
  for (long ii = (long)blockIdx.x * 256 + threadIdx.x; ii < total; ii += stride) {
    long j = ii;
    if (j < N0) { A.bar[j] = 0; continue; }
    j -= N0;
    if (j < N1) {
      int q = (int)j;
      int i = q & 7, lane = (q >> 3) & 63, nt = (q >> 9) & 1, ks = (q >> 10) & 31;
      int js = (q >> 15) & 63, cell = q >> 21;
      int gr = js * 32 + nt * 16 + (lane & 15);
      int jc = gr >> 2, g = gr & 3, k = ks * 32 + (lane >> 4) * 8 + i;
      const float* wi = cell == 0 ? A.wih0 : cell == 1 ? A.wih1 : A.wih2;
      const float* wh = cell == 0 ? A.whh0 : cell == 1 ? A.whh1 : A.whh2;
      float v;
      if (cell == 0)
        v = (k < 384) ? wi[(g * 512 + jc) * 512 + k]
          : (k < 896) ? wh[(g * 512 + jc) * 512 + k - 384]
                      : wi[(g * 512 + jc) * 512 + k - 512];
      else
        v = (k < 512) ? wi[(g * 512 + jc) * 512 + k] : wh[(g * 512 + jc) * 512 + k - 512];
      A.wr[j] = f2bf(v);
      continue;
    }
    j -= N1;
    if (j < N2) {
      int t = (int)(j / 49152); int r = (int)(j % 49152); int bb = r / 384; int e = r - bb * 384;
      int ch = (t == 0) ? 0 : A.tr[(t - 1) * 128 + bb];
      A.xemb[j] = f2bf(A.emb[ch * 384 + e]);
      continue;
    }
    j -= N2;
    A.phi_bf[j] = f2bf(A.phi_w[j]);
  }
}

// ---------------- P2: keyfT/valfT = (lf . W^T + b), stored [B][C][L] bf16
__global__ void __launch_bounds__(256) kkv(Args A) {
  __shared__ __attribute__((aligned(16))) char sm[17408 + 34816];
  UST (*A_lds)[136] = (UST(*)[136])sm;
  UST (*W_lds)[136] = (UST(*)[136])(sm + 17408);
  float* sbuf = (float*)(sm + 17408);
  int tid = threadIdx.x, lane = tid & 63, wv = tid >> 6, ln = lane & 15, qd = lane >> 4;
  int blk = blockIdx.x;
  int b = blk >> 4, lt = (blk >> 1) & 7, kv = blk & 1;
  int l0 = lt * 64;
  const float* W = kv ? A.val_w : A.key_w;
  const float* bs = kv ? A.val_b : A.key_b;
  UST* outp = kv ? A.valfT : A.keyfT;
  f32x4 acc[8];
#pragma unroll
  for (int nt = 0; nt < 8; ++nt) {
    float x = bs[nt * 16 + ln];
    f32x4 t; t[0] = x; t[1] = x; t[2] = x; t[3] = x; acc[nt] = t;
  }
  for (int cc = 0; cc < 4; ++cc) {
    int d0 = cc * 128;
#pragma unroll
    for (int it = 0; it < 8; ++it) {
      int idx = it * 256 + tid, row = idx >> 5, seg = idx & 31;
      float4 v = *(const float4*)(A.lf + ((size_t)(l0 + row) * 128 + b) * 512 + d0 + seg * 4);
      *(ushort4*)&A_lds[row][seg * 4] = f2bf4(v);
    }
#pragma unroll
    for (int it = 0; it < 16; ++it) {
      int idx = it * 256 + tid, row = idx >> 5, seg = idx & 31;
      float4 v = *(const float4*)(W + (size_t)row * 512 + d0 + seg * 4);
      *(ushort4*)&W_lds[row][seg * 4] = f2bf4(v);
    }
    __syncthreads();
#pragma unroll
    for (int ks = 0; ks < 4; ++ks) {
      s16x8 av = *(const s16x8*)&A_lds[wv * 16 + ln][ks * 32 + qd * 8];
#pragma unroll
      for (int nt = 0; nt < 8; ++nt) {
        s16x8 bv = *(const s16x8*)&W_lds[nt * 16 + ln][ks * 32 + qd * 8];
        acc[nt] = __builtin_amdgcn_mfma_f32_16x16x32_bf16(av, bv, acc[nt], 0, 0, 0);
      }
    }
    __syncthreads();
  }
#pragma unroll
  for (int nt = 0; nt < 8; ++nt)
#pragma unroll
    for (int r = 0; r < 4; ++r)
      sbuf[(wv * 16 + qd * 4 + r) * 128 + nt * 16 + ln] = acc[nt][r];
  __syncthreads();
  int c2 = tid >> 1, lh = tid & 1;
  for (int g8 = 0; g8 < 4; ++g8) {
    UST tmp[8];
#pragma unroll
    for (int i = 0; i < 8; ++i) tmp[i] = f2bf(sbuf[(lh * 32 + g8 * 8 + i) * 128 + c2]);
    *(uint4*)(outp + ((size_t)b * 128 + c2) * 512 + l0 + lh * 32 + g8 * 8) = *(uint4*)tmp;
  }
}

// ---------------- cell staging: X is 64 rows x 512 k-cols, 16B chunks XOR-swizzled.
// Block-wide form: cS = tid&63 (fixed chunk column), rB = tid>>6; row r = it*4+rB.
__device__ __forceinline__ void stage_plain(int cS, int rB, const UST* src, UST (*X)[512]) {
  uint4 rg[16];
#pragma unroll
  for (int it = 0; it < 16; ++it)
    rg[it] = ld16c(src + (it * 4 + rB) * 512 + cS * 8);
  __syncthreads();  // prior readers of X are done
#pragma unroll
  for (int it = 0; it < 16; ++it) {
    int r = it * 4 + rB;
    *(uint4*)&X[r][(cS ^ (r & 7)) * 8] = rg[it];
  }
  __syncthreads();
}
// WAVE-AUTONOMOUS staged wait: wave w owns chunk cols [16w,16w+16) — exactly the cols
// its compute slices (ls = w*4..w*4+3 -> c = ls*4+qd) read, and exactly producers
// js = 16w..16w+15. Each lane polls its own producer flag, loads its column, writes
// wave-private LDS (XOR swizzle stays inside the 16-col group since r&7 < 8). NO block
// barrier: waves slide independently past stragglers; cross-wave freshness for later
// block-wide readers is provided by subsequent epilogue barriers + IC-routed loads.
__device__ __forceinline__ void stage_wv(int w, int lane, int* fl, int val,
    const UST* src, UST (*X)[512], unsigned long long dl) {
  int cW = w * 16 + (lane & 15), rW = lane >> 4;
  while (ld_flag(&fl[cW * 16]) < val) {
    if (__builtin_amdgcn_s_memrealtime() > dl) break;
    __builtin_amdgcn_s_sleep(1);
  }
  uint4 rg[16];
#pragma unroll
  for (int it = 0; it < 16; ++it)
    rg[it] = ld16c(src + (it * 4 + rW) * 512 + cW * 8);
#pragma unroll
  for (int it = 0; it < 16; ++it) {
    int r = it * 4 + rW;
    *(uint4*)&X[r][(cW ^ (r & 7)) * 8] = rg[it];
  }
}
// emb staging: chunks 0..47 only (plain loads; xemb written by kprep).
__device__ __forceinline__ void stage_embh0(int cS, int rB, const UST* xe, const UST* h0r,
                                            UST (*X)[512]) {
  uint4 rg[16];
  if (cS < 48) {
#pragma unroll
    for (int it = 0; it < 16; ++it)
      rg[it] = *(const uint4*)(xe + (it * 4 + rB) * 384 + cS * 8);
  } else {
#pragma unroll
    for (int it = 0; it < 16; ++it)
      rg[it] = ld16c(h0r + (it * 4 + rB) * 512 + (cS - 48) * 8);
  }
  __syncthreads();
#pragma unroll
  for (int it = 0; it < 16; ++it) {
    int r = it * 4 + rB;
    *(uint4*)&X[r][(cS ^ (r & 7)) * 8] = rg[it];
  }
  __syncthreads();
}
__device__ __forceinline__ void stage_h0b(int cS, int rB, const UST* h0r, UST (*X)[512]) {
  uint4 rg[16];
  if (cS < 48) {
#pragma unroll
    for (int it = 0; it < 16; ++it)
      rg[it] = ld16c(h0r + (it * 4 + rB) * 512 + (cS + 16) * 8);
  }
  __syncthreads();
  if (cS < 48) {
#pragma unroll
    for (int it = 0; it < 16; ++it) {
      int r = it * 4 + rB;
      *(uint4*)&X[r][(cS ^ (r & 7)) * 8] = rg[it];
    }
  }
  __syncthreads();
}
// ctx staging with per-thread poll of exactly the 16 row-flags this thread reads
// (attend block b = m*64+row writes ctx row `row`; flag idx within m-half = row).
__device__ __forceinline__ void stage_ctx_poll(int cS, int rB, int* fl, int val,
    const UST* cxr, UST (*X)[512], unsigned long long dl) {
  uint4 rg[16];
  if (cS >= 48) {
    for (;;) {
      bool ok = true;
#pragma unroll
      for (int it = 0; it < 16; ++it)
        ok &= (ld_flag(&fl[(it * 4 + rB) * 16]) >= val);
      if (ok) break;
      if (__builtin_amdgcn_s_memrealtime() > dl) break;
      __builtin_amdgcn_s_sleep(1);
    }
#pragma unroll
    for (int it = 0; it < 16; ++it)
      rg[it] = ld16c(cxr + (it * 4 + rB) * 128 + (cS - 48) * 8);
  }
  __syncthreads();  // X free: all waves done with prior phase reads
  if (cS >= 48) {
#pragma unroll
    for (int it = 0; it < 16; ++it) {
      int r = it * 4 + rB;
      *(uint4*)&X[r][(cS ^ (r & 7)) * 8] = rg[it];
    }
  }
  __syncthreads();
}
// generic K-split compute: waves split SPW*4 local slices; local slice ls = w*SPW+j,
// weight k-slice ksg = ksgBase+ls, X chunk col = chunkBase + ls*4 + qd.
template <int SPW>
__device__ __forceinline__ void compute_r(int w, int ln, int qd, int lane,
    const UST* wb, int ksgBase, int chunkBase, UST (*X)[512], f32x4 acc[4][2]) {
#pragma unroll
  for (int j = 0; j < SPW; ++j) {
    int ls = w * SPW + j;
    int ksg = ksgBase + ls;
    s16x8 b0 = *(const s16x8*)(wb + ((size_t)(ksg * 2 + 0) * 64 + lane) * 8);
    s16x8 b1 = *(const s16x8*)(wb + ((size_t)(ksg * 2 + 1) * 64 + lane) * 8);
#pragma unroll
    for (int rt = 0; rt < 4; ++rt) {
      int r = rt * 16 + ln, c = chunkBase + ls * 4 + qd;
      s16x8 av = *(const s16x8*)&X[r][(c ^ (r & 7)) * 8];
      acc[rt][0] = __builtin_amdgcn_mfma_f32_16x16x32_bf16(av, b0, acc[rt][0], 0, 0, 0);
      acc[rt][1] = __builtin_amdgcn_mfma_f32_16x16x32_bf16(av, b1, acc[rt][1], 0, 0, 0);
    }
  }
}
__device__ __forceinline__ void zacc(f32x4 acc[4][2]) {
#pragma unroll
  for (int rt = 0; rt < 4; ++rt)
#pragma unroll
    for (int nt = 0; nt < 2; ++nt) {
      acc[rt][nt][0] = 0.f; acc[rt][nt][1] = 0.f; acc[rt][nt][2] = 0.f; acc[rt][nt][3] = 0.f;
    }
}
// cross-wave K-reduce in LDS + gate nonlinearity + coherent h store
__device__ __forceinline__ void cell_epilogue(const Args& A, int cell, int t, int m, int j0,
    int tid, int w, int ln, int qd, f32x4 acc[4][2], float* FB,
    const float* bias8, float* cr, UST* hdst) {
  __syncthreads();
#pragma unroll
  for (int rt = 0; rt < 4; ++rt)
#pragma unroll
    for (int nt = 0; nt < 2; ++nt)
#pragma unroll
      for (int reg = 0; reg < 4; ++reg)
        FB[w * 2112 + (rt * 16 + qd * 4 + reg) * 33 + nt * 16 + ln] = acc[rt][nt][reg];
  __syncthreads();
  int row = tid >> 2, q4 = tid & 3, grow = m * 64 + row;
  uint32 upack = 0;
#pragma unroll
  for (int jj = 0; jj < 2; ++jj) {
    int gc = (q4 * 2 + jj) * 4;
    int o = row * 33 + gc;
    float g0 = FB[o] + FB[2112 + o] + FB[4224 + o] + FB[6336 + o] + bias8[jj * 4 + 0];
    float g1 = FB[o + 1] + FB[2112 + o + 1] + FB[4224 + o + 1] + FB[6336 + o + 1] + bias8[jj * 4 + 1];
    float g2 = FB[o + 2] + FB[2112 + o + 2] + FB[4224 + o + 2] + FB[6336 + o + 2] + bias8[jj * 4 + 2];
    float g3 = FB[o + 3] + FB[2112 + o + 3] + FB[4224 + o + 3] + FB[6336 + o + 3] + bias8[jj * 4 + 3];
    float cn = sigf(g1) * cr[jj] + sigf(g0) * tanhf_(g2);
    float hv = sigf(g3) * tanhf_(cn);
    cr[jj] = cn;
    upack |= ((uint32)f2bf(hv)) << (16 * jj);
  }
  st4(hdst + grow * 512 + j0 + q4 * 2, upack);
  if (cell == 2) *(uint32*)(A.h2h + ((size_t)t * 128 + grow) * 512 + j0 + q4 * 2) = upack;
}

// ---------------- attention (blocks 128..255, one batch row each)
// K and V live in per-thread REGISTERS (preloaded once). hx2 pickup merges a per-thread
// poll of exactly this thread's column-producer flag (js = tid>>1) with the 8B load.
__device__ __forceinline__ void attend_f(const Args& A, int t, int p, int b, int tid,
    int lane, int wv, char* smraw, const uint4 (&rgK)[32], const uint4 (&rgV)[32],
    int* pf, int pv, unsigned long long dl) {
  float* att_h = (float*)smraw;                       // 512
  float* att_q = att_h + 512;                         // 256
  float* att_c = att_q + 256;                         // 128
  float* att_red = att_c + 128;                       // 16
  float (*e_part)[512] = (float(*)[512])(att_red + 16);
  const UST* hx2p = A.hx2 + p * 65536;
  if (tid < 128) {
    const int* fp = &pf[(tid >> 1) * 16];
    while (ld_flag(fp) < pv) {
      if (__builtin_amdgcn_s_memrealtime() > dl) break;
      __builtin_amdgcn_s_sleep(1);
    }
    U8 v; v.u = ld8(hx2p + b * 512 + tid * 4);
    att_h[tid * 4 + 0] = b2f(v.s.x); att_h[tid * 4 + 1] = b2f(v.s.y);
    att_h[tid * 4 + 2] = b2f(v.s.z); att_h[tid * 4 + 3] = b2f(v.s.w);
  }
  __syncthreads();
  int c = tid & 127, half = tid >> 7;
  { // q = phi_b + phi . hx2 (phi streamed from L2; shared across 16 blocks/XCD)
    float acc = half ? 0.f : A.phi_b[c];
    const UST* pr = A.phi_bf + c * 512 + half * 256;
    const float* hh = att_h + half * 256;
#pragma unroll 4
    for (int k = 0; k < 256; k += 8) {
      uint4 v = *(const uint4*)(pr + k);
      const UST* us = (const UST*)&v;
#pragma unroll
      for (int i = 0; i < 8; ++i) acc += b2f(us[i]) * hh[k + i];
    }
    att_q[tid] = acc;
  }
  __syncthreads();
  if (tid < 128) att_q[tid] += att_q[tid + 128];
  __syncthreads();
  { // energies from K registers: thread (cg,lg) covers c in [cg*32,cg*32+32), l = lg*8+i
    int cg = tid >> 6, lg = tid & 63;
    float ep[8] = {0, 0, 0, 0, 0, 0, 0, 0};
#pragma unroll
    for (int i = 0; i < 32; ++i) {
      float qv = att_q[cg * 32 + i];
      const UST* us = (const UST*)&rgK[i];
#pragma unroll
      for (int j = 0; j < 8; ++j) ep[j] += qv * b2f(us[j]);
    }
#pragma unroll
    for (int i = 0; i < 8; ++i) e_part[cg][lg * 8 + i] = ep[i];
  }
  __syncthreads();
  float e0 = e_part[0][2 * tid] + e_part[1][2 * tid] + e_part[2][2 * tid] + e_part[3][2 * tid];
  float e1 = e_part[0][2 * tid + 1] + e_part[1][2 * tid + 1] + e_part[2][2 * tid + 1] + e_part[3][2 * tid + 1];
  float mx = fmaxf(e0, e1);
#pragma unroll
  for (int off = 32; off; off >>= 1) mx = fmaxf(mx, __shfl_xor(mx, off));
  if (lane == 0) att_red[wv] = mx;
  __syncthreads();
  mx = fmaxf(fmaxf(att_red[0], att_red[1]), fmaxf(att_red[2], att_red[3]));
  int len = A.ulen[b];
  float x0 = (2 * tid < len) ? __expf(e0 - mx) : 0.f;
  float x1 = (2 * tid + 1 < len) ? __expf(e1 - mx) : 0.f;
  float s = x0 + x1;
#pragma unroll
  for (int off = 32; off; off >>= 1) s += __shfl_xor(s, off);
  if (lane == 0) att_red[8 + wv] = s;
  __syncthreads();
  s = att_red[8] + att_red[9] + att_red[10] + att_red[11];
  float inv = 1.f / fmaxf(s, 1e-12f);
  float a0 = x0 * inv, a1 = x1 * inv;
  float* esm = &e_part[0][0];
  esm[2 * tid] = a0; esm[2 * tid + 1] = a1;
  if (t >= 0) {
    float2 st; st.x = a0; st.y = a1;
    *(float2*)(A.out_attn + ((size_t)t * 128 + b) * 512 + 2 * tid) = st;
  }
  __syncthreads();
  { // ctx[c] = sum_l a_l * V[c][l] from V registers; thread (c,half) covers l half*256..+256
    float acc = 0.f;
    const float* aa = esm + half * 256;
#pragma unroll
    for (int i = 0; i < 32; ++i) {
      const UST* us = (const UST*)&rgV[i];
#pragma unroll
      for (int j = 0; j < 8; ++j) acc += aa[i * 8 + j] * b2f(us[j]);
    }
    att_q[tid] = acc;
  }
  __syncthreads();
  if (tid < 128) att_c[tid] = att_q[tid] + att_q[tid + 128];
  __syncthreads();
  if (tid < 64) {
    float cv0 = att_c[2 * tid], cv1 = att_c[2 * tid + 1];
    uint32 u = (uint32)f2bf(cv0) | ((uint32)f2bf(cv1) << 16);
    st4(A.ctx + p * 16384 + b * 128 + 2 * tid, u);
    if (t >= 0) *(uint32*)(A.cxh + ((size_t)t * 128 + b) * 128 + 2 * tid) = u;
  }
}

// ---------------- main persistent kernel. PLAIN launch (not cooperative): sync is
// hand-rolled flags; co-residency by capacity arithmetic (LDS 64KB, grid 256 <= 256 CUs,
// 1 block/CU at 4 waves = 1 wave/SIMD). Flags indexed sid = m*64+js; all steady-state
// dependencies stay within one m-half. All waits deadline-bounded (~1 s).
// Per-step schedule (cell blocks):
//   pre : phase A emb+h0(t-1)lo -> c0 sl0..15 | phase B h0(t-1)hi -> c0 sl16..27
//         stage h1(t-1) -> c1 K16..31 | stage_wv h2(t-1) [mc2 t+1] -> c2 K16..31
//   seg1: stage_ctx_poll [mat rows t+1] -> c0 sl28..31, epi0, sig c0
//   seg3: stage_wv h0(t) [mc0 t+2] -> c1 K0..15, epi1, sig c1
//   seg4: stage_wv h1(t) [mc1 t+2] -> c2 K0..15, epi2, sig c2
// stage_wv phases are barrier-free (wave-private LDS cols, per-wave producer polls).
__global__ void __launch_bounds__(256) kmain(Args A) {
  __shared__ __attribute__((aligned(16))) char smraw[65536];
  unsigned long long dl = __builtin_amdgcn_s_memrealtime() + 100000000ull;
  int blk = blockIdx.x, tid = threadIdx.x;
  int lane = tid & 63, w = tid >> 6, ln = lane & 15, qd = lane >> 4;
  int* c0f = A.bar;
  int* c1f = A.bar + 2048;
  int* c2f = A.bar + 4096;
  int* attf = A.bar + 6144;
  if (blk < 128) {
    UST (*X)[512] = (UST(*)[512])smraw;   // 64 KB staging
    float* FB = (float*)smraw;            // 33,792 B epilogue reduce (aliased)
    // same-XCD weight-slab pairing: blk and blk^8 share js and land on one XCD
    int js = ((blk >> 4) << 3) | (blk & 7);
    int m = (blk >> 3) & 1;
    int j0 = js * 8;
    int sid = m * 64 + js;
    int* mc0 = c0f + m * 1024;   // this half's 64 flags
    int* mc1 = c1f + m * 1024;
    int* mc2 = c2f + m * 1024;
    int* mat = attf + m * 1024;
    int cS = tid & 63, rB = tid >> 6;
    float bias[3][8]; float cr[3][2];
    {
      const float* bihA[3] = {A.bih0, A.bih1, A.bih2};
      const float* bhhA[3] = {A.bhh0, A.bhh1, A.bhh2};
      const float* icxA[3] = {A.icx0, A.icx1, A.icx2};
      const float* ihxA[3] = {A.ihx0, A.ihx1, A.ihx2};
      UST* hxA[3] = {A.hx0, A.hx1, A.hx2};
      int q4 = tid & 3;
#pragma unroll
      for (int cI = 0; cI < 3; ++cI) {
#pragma unroll
        for (int jj = 0; jj < 2; ++jj) {
          int col = j0 + q4 * 2 + jj;
          for (int g = 0; g < 4; ++g)
            bias[cI][jj * 4 + g] = bihA[cI][g * 512 + col] + bhhA[cI][g * 512 + col];
          cr[cI][jj] = icxA[cI][col];
        }
        int row = tid >> 2, grow = m * 64 + row, col0 = j0 + q4 * 2;
        uint32 u = (uint32)f2bf(ihxA[cI][col0]) | ((uint32)f2bf(ihxA[cI][col0 + 1]) << 16);
        st4(hxA[cI] + 65536 + grow * 512 + col0, u);  // init into slot 1
      }
    }
    signal_flag(c2f, sid, 1, tid);
    wait128f(c2f, 1, tid, dl);
    const UST* wrj0 = A.wr + (size_t)js * 32768;
    const UST* wrj1 = wrj0 + 2097152;
    const UST* wrj2 = wrj0 + 4194304;
    f32x4 acc0[4][2], acc1[4][2], acc2[4][2];
    for (int t = 0; t < 200; ++t) {
      int p = t & 1, po = p ^ 1;
      const UST* xe = A.xemb + (size_t)t * 49152 + m * 64 * 384;
      const UST* h0r = A.hx0 + po * 65536 + m * 64 * 512;
      const UST* h1r = A.hx1 + po * 65536 + m * 64 * 512;
      const UST* h2r = A.hx2 + po * 65536 + m * 64 * 512;
      const UST* cxr = A.ctx + po * 16384 + m * 64 * 128;
      zacc(acc0); zacc(acc1); zacc(acc2);
      // ---- pre-wait work (overlaps attend on other CUs) ----
      // c0 phase A: k 0..511 = emb(384) + h0(t-1) cols 0..127 (h0(t-1) synced last step)
      stage_embh0(cS, rB, xe, h0r, X);
      compute_r<4>(w, ln, qd, lane, wrj0, 0, 0, X, acc0);
      // c0 phase B: k 512..895 = h0(t-1) cols 128..511
      stage_h0b(cS, rB, h0r, X);
      compute_r<3>(w, ln, qd, lane, wrj0, 16, 0, X, acc0);
      // c1 pre-half: h1(t-1) (synced via mc1 polls last step + barriers)
      stage_plain(cS, rB, h1r, X);
      compute_r<4>(w, ln, qd, lane, wrj1, 16, 0, X, acc1);
      // c2 pre-half: h2(t-1); wave-autonomous poll (nearly always already satisfied)
      stage_wv(w, lane, mc2, t + 1, h2r, X, dl);
      compute_r<4>(w, ln, qd, lane, wrj2, 16, 0, X, acc2);
      // ---- post-wait critical path ----
      // seg1: ctx(t) slices + epilogue0 (per-thread row-flag polls merged into staging)
      stage_ctx_poll(cS, rB, mat, t + 1, cxr, X, dl);
      compute_r<1>(w, ln, qd, lane, wrj0, 28, 48, X, acc0);
      cell_epilogue(A, 0, t, m, j0, tid, w, ln, qd, acc0, FB, bias[0], cr[0], A.hx0 + p * 65536);
      signal_flag(c0f, sid, t + 2, tid);
      // seg3: cell1 finish — h0(t), wave-autonomous
      const UST* h0n = A.hx0 + p * 65536 + m * 64 * 512;
      stage_wv(w, lane, mc0, t + 2, h0n, X, dl);
      compute_r<4>(w, ln, qd, lane, wrj1, 0, 0, X, acc1);
      cell_epilogue(A, 1, t, m, j0, tid, w, ln, qd, acc1, FB, bias[1], cr[1], A.hx1 + p * 65536);
      signal_flag(c1f, sid, t + 2, tid);
      // seg4: cell2 finish — h1(t), wave-autonomous
      const UST* h1n = A.hx1 + p * 65536 + m * 64 * 512;
      stage_wv(w, lane, mc1, t + 2, h1n, X, dl);
      compute_r<4>(w, ln, qd, lane, wrj2, 0, 0, X, acc2);
      cell_epilogue(A, 2, t, m, j0, tid, w, ln, qd, acc2, FB, bias[2], cr[2], A.hx2 + p * 65536);
      signal_flag(c2f, sid, t + 2, tid);
      // no wait at loop bottom: next phase A's h0(t) freshness is guaranteed by the
      // collective mc0 polls (all 64 flags observed across waves) + epilogue barriers,
      // and all h reads are IC-routed (ld16c).
    }
  } else {
    int b = blk - 128;
    int* mc2a = c2f + (b >> 6) * 1024;  // this row's m-half c2 flags
    // preload K,V into registers (written by kkv, which completed before kmain)
    uint4 rgK[32], rgV[32];
    {
      int cg = tid >> 6, lg = tid & 63;
      const UST* kb = A.keyfT + (size_t)b * 65536 + lg * 8;
#pragma unroll
      for (int i = 0; i < 32; ++i)
        rgK[i] = *(const uint4*)(kb + (size_t)(cg * 32 + i) * 512);
      int c = tid & 127, half = tid >> 7;
      const UST* vb = A.valfT + (size_t)b * 65536 + (size_t)c * 512 + half * 256;
#pragma unroll
      for (int i = 0; i < 32; ++i)
        rgV[i] = *(const uint4*)(vb + i * 8);
    }
    attend_f(A, -1, 1, b, tid, lane, w, smraw, rgK, rgV, mc2a, 1, dl);
    signal_flag(attf, b, 1, tid);
    for (int t = 0; t < 200; ++t) {
      attend_f(A, t, t & 1, b, tid, lane, w, smraw, rgK, rgV, mc2a, t + 2, dl);
      signal_flag(attf, b, t + 2, tid);
    }
  }
}

// ---------------- epilogue: logits[t,b,v] = [hx2,ctx] . out_w^T + out_b
__global__ void __launch_bounds__(256) kepi(Args A) {
  __shared__ UST ow[46 * 648];
  __shared__ float ob[46];
  int t = blockIdx.x, tid = threadIdx.x;
  for (int i = tid; i < 46 * 640; i += 256) {
    int v = i / 640, k = i - v * 640; ow[v * 648 + k] = f2bf(A.out_w[i]);
  }
  if (tid < 46) ob[tid] = A.out_b[tid];
  __syncthreads();
  for (int oi = tid; oi < 128 * 46; oi += 256) {
    int bb = oi / 46, v = oi - bb * 46;
    const UST* xh = A.h2h + ((size_t)t * 128 + bb) * 512;
    const UST* xc = A.cxh + ((size_t)t * 128 + bb) * 128;
    const UST* wrow = &ow[v * 648];
    float acc = ob[v];
    for (int k = 0; k < 512; k += 8) {
      uint4 xv = *(const uint4*)(xh + k);
      uint4 wv4 = *(const uint4*)(wrow + k);
      const UST* xs = (const UST*)&xv; const UST* wl = (const UST*)&wv4;
#pragma unroll
      for (int i = 0; i < 8; ++i) acc += b2f(xs[i]) * b2f(wl[i]);
    }
    for (int k = 0; k < 128; k += 8) {
      uint4 xv = *(const uint4*)(xc + k);
      uint4 wv4 = *(const uint4*)(wrow + 512 + k);
      const UST* xs = (const UST*)&xv; const UST* wl = (const UST*)&wv4;
#pragma unroll
      for (int i = 0; i < 8; ++i) acc += b2f(xs[i]) * b2f(wl[i]);
    }
    A.out_logits[((size_t)t * 128 + bb) * 46 + v] = acc;
  }
}

extern "C" void kernel_launch(void* const* d_in, const int* in_sizes, int n_in,
                              void* d_out, int out_size, void* d_ws, size_t ws_size,
                              hipStream_t stream) {
  (void)in_sizes; (void)n_in; (void)out_size; (void)ws_size;
  Args a;
  a.lf = (const float*)d_in[0]; a.ulen = (const int*)d_in[1]; a.tr = (const int*)d_in[2];
  a.emb = (const float*)d_in[3];
  a.wih0 = (const float*)d_in[4]; a.whh0 = (const float*)d_in[5]; a.bih0 = (const float*)d_in[6]; a.bhh0 = (const float*)d_in[7];
  a.wih1 = (const float*)d_in[8]; a.whh1 = (const float*)d_in[9]; a.bih1 = (const float*)d_in[10]; a.bhh1 = (const float*)d_in[11];
  a.wih2 = (const float*)d_in[12]; a.whh2 = (const float*)d_in[13]; a.bih2 = (const float*)d_in[14]; a.bhh2 = (const float*)d_in[15];
  a.phi_w = (const float*)d_in[16]; a.phi_b = (const float*)d_in[17];
  a.key_w = (const float*)d_in[18]; a.key_b = (const float*)d_in[19];
  a.val_w = (const float*)d_in[20]; a.val_b = (const float*)d_in[21];
  a.out_w = (const float*)d_in[22]; a.out_b = (const float*)d_in[23];
  a.ihx0 = (const float*)d_in[24]; a.icx0 = (const float*)d_in[25];
  a.ihx1 = (const float*)d_in[26]; a.icx1 = (const float*)d_in[27];
  a.ihx2 = (const float*)d_in[28]; a.icx2 = (const float*)d_in[29];
  char* ws = (char*)d_ws;
  a.bar    = (int*)ws;                   // 32,768 B (4 flag arrays x 128 x 16 ints)
  a.wr     = (UST*)(ws + 32768);         // 12,582,912 B
  a.xemb   = (UST*)(ws + 12615680);      // 19,660,800 B
  a.phi_bf = (UST*)(ws + 32276480);      // 131,072 B
  a.keyfT  = (UST*)(ws + 32407552);      // 16,777,216 B
  a.valfT  = (UST*)(ws + 49184768);      // 16,777,216 B
  a.hx0    = (UST*)(ws + 65961984);      // 262,144 B (2 slots)
  a.hx1    = (UST*)(ws + 66224128);      // 262,144 B
  a.hx2    = (UST*)(ws + 66486272);      // 262,144 B
  a.ctx    = (UST*)(ws + 66748416);      // 65,536 B (2 slots)
  a.h2h    = (UST*)(ws + 66813952);      // 26,214,400 B
  a.cxh    = (UST*)(ws + 93028352);      // 6,553,600 B -> total 99,581,952 B
  a.out_logits = (float*)d_out;
  a.out_attn   = (float*)d_out + 1177600;
  kprep<<<4096, 256, 0, stream>>>(a);
  kkv<<<2048, 256, 0, stream>>>(a);
  kmain<<<256, 256, 0, stream>>>(a);
  kepi<<<200, 256, 0, stream>>>(a);
}